// Round 4
// baseline (115.615 us; speedup 1.0000x reference)
//
#include <hip/hip_runtime.h>

// PointNet 3-NN feature interpolation, v3: seed-threshold + filtered scan.
// knn3_seed : full top-3 scan of chunk 0 (512 pts) -> c=0 partials + tau0.
// knn3_main : chunks 1..15, distance + filter (d <= tau0) + rare masked insert.
// knn3_merge: merge per-chunk top-3s (exact, ascending order), weights.
// interp    : per-(b,d) row staged in LDS, gather+weighted-sum.

constexpr int QT = 256;        // queries per block in knn3_main
constexpr int MAXCHUNK = 1024; // LDS capacity (float4 per point)

__device__ __forceinline__ void insert3b(float& d0, float& d1, float& d2,
                                         int& i0, int& i1, int& i2,
                                         float d, int n) {
    bool c0 = d < d0, c1 = d < d1, c2 = d < d2;
    float nd2 = c1 ? d1 : (c2 ? d : d2);
    int   ni2 = c1 ? i1 : (c2 ? n : i2);
    float nd1 = c0 ? d0 : (c1 ? d : d1);
    int   ni1 = c0 ? i0 : (c1 ? n : i1);
    float nd0 = c0 ? d  : d0;
    int   ni0 = c0 ? n  : i0;
    d0 = nd0; d1 = nd1; d2 = nd2;
    i0 = ni0; i1 = ni1; i2 = ni2;
}

// Stage cs points as {2x, 2y, 2z, norm}. (qx*2x + qy*2y) + qz*2z rounds
// bit-identically to 2*((qx*x + qy*y) + qz*z): pow2 scaling commutes with
// rounding. norm = (x*x + y*y) + z*z, np's sum order.
template <int BLK>
__device__ __forceinline__ void stage_chunk(float4* spt,
                                            const float* __restrict__ bx,
                                            const float* __restrict__ by,
                                            const float* __restrict__ bz,
                                            int cs, int tid) {
#pragma clang fp contract(off)
    for (int i = tid * 4; i < cs; i += BLK * 4) {
        float4 vx = *reinterpret_cast<const float4*>(bx + i);
        float4 vy = *reinterpret_cast<const float4*>(by + i);
        float4 vz = *reinterpret_cast<const float4*>(bz + i);
        spt[i + 0] = make_float4(vx.x + vx.x, vy.x + vy.x, vz.x + vz.x,
                                 (vx.x*vx.x + vy.x*vy.x) + vz.x*vz.x);
        spt[i + 1] = make_float4(vx.y + vx.y, vy.y + vy.y, vz.y + vz.y,
                                 (vx.y*vx.y + vy.y*vy.y) + vz.y*vz.y);
        spt[i + 2] = make_float4(vx.z + vx.z, vy.z + vy.z, vz.z + vz.z,
                                 (vx.z*vx.z + vy.z*vy.z) + vz.z*vz.z);
        spt[i + 3] = make_float4(vx.w + vx.w, vy.w + vy.w, vz.w + vz.w,
                                 (vx.w*vx.w + vy.w*vy.w) + vz.w*vz.w);
    }
}

__global__ __launch_bounds__(64)
void knn3_seed(const float* __restrict__ xyz1, const float* __restrict__ xyz2,
               int B, int N, int S, int cs,
               float* __restrict__ pd0, float* __restrict__ pd1,
               float* __restrict__ pd2,
               int* __restrict__ pi0, int* __restrict__ pi1,
               int* __restrict__ pi2, float* __restrict__ tau)
{
#pragma clang fp contract(off)
    __shared__ float4 spt[MAXCHUNK];
    const int tid = threadIdx.x;
    const int q   = blockIdx.x * 64 + tid;
    const int b   = q / S;                    // 64 | S
    const int s   = q - b * S;

    const float* __restrict__ bx = xyz1 + (size_t)b * 3 * N;
    stage_chunk<64>(spt, bx, bx + N, bx + 2 * N, cs, tid);
    __syncthreads();

    const float* __restrict__ q2p = xyz2 + (size_t)b * 3 * S;
    const float qx = q2p[s];
    const float qy = q2p[S + s];
    const float qz = q2p[2 * S + s];
    const float qss = (qx * qx + qy * qy) + qz * qz;

    float d0 = 3.4e38f, d1 = 3.4e38f, d2 = 3.4e38f;
    int   i0 = 0, i1 = 0, i2 = 0;
#pragma unroll 4
    for (int k = 0; k < cs; ++k) {
        float4 p = spt[k];
        float dot2 = (qx * p.x + qy * p.y) + qz * p.z;   // == 2*dot, exact
        float d    = (qss + p.w) - dot2;
        insert3b(d0, d1, d2, i0, i1, i2, d, k);
    }
    pd0[q] = d0; pd1[q] = d1; pd2[q] = d2;
    pi0[q] = i0; pi1[q] = i1; pi2[q] = i2;
    tau[q] = d2;
}

__global__ __launch_bounds__(256)
void knn3_main(const float* __restrict__ xyz1, const float* __restrict__ xyz2,
               const float* __restrict__ tau,
               int B, int N, int S, int cs, int BS,
               float* __restrict__ pd0, float* __restrict__ pd1,
               float* __restrict__ pd2,
               int* __restrict__ pi0, int* __restrict__ pi1,
               int* __restrict__ pi2)
{
#pragma clang fp contract(off)
    __shared__ float4 spt[MAXCHUNK];
    const int tid = threadIdx.x;
    const int q   = blockIdx.x * QT + tid;
    const int c   = blockIdx.y + 1;           // chunks 1..nChunk-1
    const int b   = q / S;                    // QT | S
    const int s   = q - b * S;
    const int n0  = c * cs;

    const float* __restrict__ bx = xyz1 + (size_t)b * 3 * N + n0;
    stage_chunk<256>(spt, bx, bx + N, bx + 2 * N, cs, tid);
    __syncthreads();

    const float* __restrict__ q2p = xyz2 + (size_t)b * 3 * S;
    const float qx = q2p[s];
    const float qy = q2p[S + s];
    const float qz = q2p[2 * S + s];
    const float qss = (qx * qx + qy * qy) + qz * qz;
    const float t0  = tau[q];

    float d0 = 3.4e38f, d1 = 3.4e38f, d2 = 3.4e38f;
    int   i0 = 0, i1 = 0, i2 = 0;
#pragma unroll 4
    for (int k = 0; k < cs; ++k) {
        float4 p = spt[k];
        float dot2 = (qx * p.x + qy * p.y) + qz * p.z;   // == 2*dot, exact
        float d    = (qss + p.w) - dot2;
        if (d <= t0)                         // exec-masked, rarely taken
            insert3b(d0, d1, d2, i0, i1, i2, d, n0 + k);
    }
    const size_t off = (size_t)c * BS + q;
    pd0[off] = d0; pd1[off] = d1; pd2[off] = d2;
    pi0[off] = i0; pi1[off] = i1; pi2[off] = i2;
}

__global__ __launch_bounds__(256)
void knn3_merge(const float* __restrict__ pd0, const float* __restrict__ pd1,
                const float* __restrict__ pd2,
                const int* __restrict__ pi0, const int* __restrict__ pi1,
                const int* __restrict__ pi2,
                int nChunk, int BS,
                int* __restrict__ idx0, int* __restrict__ idx1, int* __restrict__ idx2,
                float* __restrict__ w0, float* __restrict__ w1, float* __restrict__ w2)
{
#pragma clang fp contract(off)
    const int q = blockIdx.x * 256 + threadIdx.x;
    if (q >= BS) return;
    float d0 = 3.4e38f, d1 = 3.4e38f, d2 = 3.4e38f;
    int   i0 = 0, i1 = 0, i2 = 0;
    for (int c = 0; c < nChunk; ++c) {
        const size_t off = (size_t)c * BS + q;
        insert3b(d0, d1, d2, i0, i1, i2, pd0[off], pi0[off]);
        insert3b(d0, d1, d2, i0, i1, i2, pd1[off], pi1[off]);
        insert3b(d0, d1, d2, i0, i1, i2, pd2[off], pi2[off]);
    }
    const float r0 = 1.0f / (d0 + 1e-8f);
    const float r1 = 1.0f / (d1 + 1e-8f);
    const float r2 = 1.0f / (d2 + 1e-8f);
    const float sum = (r0 + r1) + r2;
    idx0[q] = i0; idx1[q] = i1; idx2[q] = i2;
    w0[q] = r0 / sum; w1[q] = r1 / sum; w2[q] = r2 / sum;
}

__global__ __launch_bounds__(256)
void interp_kernel(const float* __restrict__ points1,
                   const int* __restrict__ idx0, const int* __restrict__ idx1,
                   const int* __restrict__ idx2,
                   const float* __restrict__ w0, const float* __restrict__ w1,
                   const float* __restrict__ w2,
                   float* __restrict__ out, int N, int S, int D)
{
#pragma clang fp contract(off)
    __shared__ float row[8192];
    const int bd = blockIdx.x;
    const int b  = bd / D;
    const float* __restrict__ src = points1 + (size_t)bd * N;

    for (int i = threadIdx.x * 4; i < N; i += blockDim.x * 4) {
        *reinterpret_cast<float4*>(&row[i]) =
            *reinterpret_cast<const float4*>(src + i);
    }
    __syncthreads();

    float* __restrict__ dst = out + (size_t)bd * S;
    const int qb = b * S;
    for (int s = threadIdx.x; s < S; s += blockDim.x) {
        int q = qb + s;
        float a = row[idx0[q]] * w0[q];
        float c = row[idx1[q]] * w1[q];
        float e = row[idx2[q]] * w2[q];
        dst[s] = (a + c) + e;
    }
}

extern "C" void kernel_launch(void* const* d_in, const int* in_sizes, int n_in,
                              void* d_out, int out_size, void* d_ws, size_t ws_size,
                              hipStream_t stream) {
    const float* xyz1    = (const float*)d_in[0];
    const float* xyz2    = (const float*)d_in[1];
    const float* points1 = (const float*)d_in[2];
    float* out = (float*)d_out;

    const int B = 8;
    const int N = in_sizes[0] / (3 * B);
    const int S = in_sizes[1] / (3 * B);
    const int D = in_sizes[2] / (B * N);
    const int BS = B * S;

    int nChunk = 16;
    auto wsNeed = [&](int nc) {
        return (size_t)nc * BS * 6 * 4 + (size_t)BS * 7 * 4;
    };
    if (wsNeed(16) > ws_size) nChunk = 8;
    const int cs = N / nChunk;            // 512 or 1024 (<= MAXCHUNK)

    float* pd0 = (float*)d_ws;
    float* pd1 = pd0 + (size_t)nChunk * BS;
    float* pd2 = pd1 + (size_t)nChunk * BS;
    int*   pi0 = (int*)(pd2 + (size_t)nChunk * BS);
    int*   pi1 = pi0 + (size_t)nChunk * BS;
    int*   pi2 = pi1 + (size_t)nChunk * BS;
    int*   idx0 = pi2 + (size_t)nChunk * BS;
    int*   idx1 = idx0 + BS;
    int*   idx2 = idx1 + BS;
    float* w0   = (float*)(idx2 + BS);
    float* w1   = w0 + BS;
    float* w2   = w1 + BS;
    float* tau  = w2 + BS;

    // Seed: chunk 0 full scan, one wave per 64 queries (spreads over 256 CUs).
    knn3_seed<<<BS / 64, 64, 0, stream>>>(xyz1, xyz2, B, N, S, cs,
                                          pd0, pd1, pd2, pi0, pi1, pi2, tau);

    // Main: chunks 1..nChunk-1 with threshold filter.
    dim3 g1(BS / QT, nChunk - 1);
    knn3_main<<<g1, 256, 0, stream>>>(xyz1, xyz2, tau, B, N, S, cs, BS,
                                      pd0, pd1, pd2, pi0, pi1, pi2);

    knn3_merge<<<(BS + 255) / 256, 256, 0, stream>>>(pd0, pd1, pd2, pi0, pi1, pi2,
                                                     nChunk, BS,
                                                     idx0, idx1, idx2, w0, w1, w2);

    interp_kernel<<<B * D, 256, 0, stream>>>(points1, idx0, idx1, idx2,
                                             w0, w1, w2, out, N, S, D);
}